// Round 9
// baseline (211.824 us; speedup 1.0000x reference)
//
#include <hip/hip_runtime.h>
#include <math.h>

#define Bg 256
#define Nn 4096
#define Ee 65536
#define Kk (Nn * 3)   // 12288

__device__ __forceinline__ unsigned bf16r(float v) {   // fp32 -> bf16 bits, RNE
    unsigned b = __float_as_uint(v);
    return (b + 0x7fffu + ((b >> 16) & 1u)) >> 16;
}

// ---------------- fused prep + transpose (independent halves) ----------------
// blocks [0,256): raw-bf16 transpose of x into 4 batch slabs (no scale)
// blocks [256,512): edge prep (deg_out histogram + capacity-64 CSR by dst);
//                   ticket-elected last prep block builds c_srcf[4096].
__global__ __launch_bounds__(256) void k_pt(const float* __restrict__ x,
                                            const int* __restrict__ src,
                                            const int* __restrict__ dst,
                                            int* __restrict__ deg_out,
                                            int* __restrict__ cursor,
                                            int* __restrict__ csr,
                                            int* __restrict__ done,
                                            float* __restrict__ c_srcf,
                                            uint2* __restrict__ xsb) {
    int id = blockIdx.x;
    int t = threadIdx.x;
    if (id < 256) {
        __shared__ float4 tile4[64][49];           // row stride 196 floats
        int bq = id >> 6;                          // batch slab [0,4)
        int n0 = (id & 63) * 64;                   // node group
        const float* xb = x + (size_t)bq * 64 * Kk + (size_t)n0 * 3;
#pragma unroll
        for (int i = 0; i < 12; i++) {
            int idx = i * 256 + t;
            int bi = idx / 48, j = idx - bi * 48;
            tile4[bi][j] = ((const float4*)(xb + (size_t)bi * Kk))[j];
        }
        __syncthreads();
        const float* tile = (const float*)tile4;   // [64][196]
        uint2* outp = xsb + ((size_t)bq * Nn + n0) * 64;
#pragma unroll
        for (int i = 0; i < 16; i++) {
            int idx = i * 256 + t;
            int nn = idx >> 6, bl = idx & 63;      // per wave: nn fixed, bl = lane
            float f0 = tile[bl * 196 + nn * 3 + 0];
            float f1 = tile[bl * 196 + nn * 3 + 1];
            float f2 = tile[bl * 196 + nn * 3 + 2];
            uint2 u;
            u.x = bf16r(f0) | (bf16r(f1) << 16);
            u.y = bf16r(f2);
            outp[(size_t)nn * 64 + bl] = u;
        }
    } else {
        __shared__ int lastp;
        int e = (id - 256) * 256 + t;
        int s = src[e], d = dst[e];
        atomicAdd(&deg_out[s], 1);
        int ofs = atomicAdd(&cursor[d], 1) & 63;   // capacity 64 (max in-deg ~35 << 64)
        csr[(d << 6) + ofs] = s;
        __threadfence();
        __syncthreads();
        if (t == 0) lastp = (atomicAdd(done, 1) == 255);
        __syncthreads();
        if (lastp) {
            for (int i = t; i < Nn; i += 256) {
                int dv = atomicAdd(&deg_out[i], 0);            // read-through L2
                c_srcf[i] = rsqrtf(fmaxf((float)dv, 1.0f));
            }
        }
    }
}

// ---------------- fused gather + c_src + (3->64) matmul + relu + Wfc dot + reduce + sigmoid ---
// 4 waves/block, one node per wave; lane = batch element within slab.
// Edge ids AND their c_src scales loaded once per wave, broadcast via __shfl.
// Epilogue: w0-wave atomicAdd into 16x256 bins; ticket-elected last block
// sums bins + sigmoid.
__global__ __launch_bounds__(256) void k_mega(const uint2* __restrict__ xsb,
                                              const float* __restrict__ W1,
                                              const float* __restrict__ b1,
                                              const float* __restrict__ Wfc,
                                              const int* __restrict__ cursor,
                                              const int* __restrict__ csr,
                                              const float* __restrict__ c_srcf,
                                              float* __restrict__ bins,
                                              int* __restrict__ ticket,
                                              const float* __restrict__ bfc,
                                              float* __restrict__ out) {
    __shared__ float4 sW14[64];
    __shared__ float sWfc[4][64];
    __shared__ float red[4][64];
    __shared__ int lastflag;
    int t = threadIdx.x & 63;
    int w = threadIdx.x >> 6;
    int bq = blockIdx.x & 3;            // slab; round-robin dispatch -> XCD k sees one bq
    int g  = blockIdx.x >> 2;           // node group [0,1024)
    int n  = g * 4 + w;
    if (w == 0) sW14[t] = make_float4(W1[t], W1[64 + t], W1[128 + t], b1[t]);
    sWfc[w][t] = Wfc[n * 64 + t];
    __syncthreads();

    const uint2* slab = xsb + (size_t)bq * (Nn * 64);
    int deg = cursor[n]; if (deg > 64) deg = 64;
    int myedge = csr[(n << 6) + t];     // whole edge list in one wave load
    if (t >= deg) myedge = 0;           // unused slots may hold poison -> clamp
    float myq = c_srcf[myedge];         // per-edge source scale, one gather/wave
    float a0 = 0.f, a1 = 0.f, a2 = 0.f;
    float c0 = 0.f, c1 = 0.f, c2 = 0.f;
    int i = 0;
    for (; i + 4 <= deg; i += 4) {
        int s0 = __shfl(myedge, i);     float q0 = __shfl(myq, i);
        int s1 = __shfl(myedge, i + 1); float q1 = __shfl(myq, i + 1);
        int s2 = __shfl(myedge, i + 2); float q2 = __shfl(myq, i + 2);
        int s3 = __shfl(myedge, i + 3); float q3 = __shfl(myq, i + 3);
        uint2 u0 = slab[(s0 << 6) + t];
        uint2 u1 = slab[(s1 << 6) + t];
        uint2 u2 = slab[(s2 << 6) + t];
        uint2 u3 = slab[(s3 << 6) + t];
        a0 = fmaf(__uint_as_float(u0.x << 16), q0, a0);
        a1 = fmaf(__uint_as_float(u0.x & 0xffff0000u), q0, a1);
        a2 = fmaf(__uint_as_float(u0.y << 16), q0, a2);
        c0 = fmaf(__uint_as_float(u1.x << 16), q1, c0);
        c1 = fmaf(__uint_as_float(u1.x & 0xffff0000u), q1, c1);
        c2 = fmaf(__uint_as_float(u1.y << 16), q1, c2);
        a0 = fmaf(__uint_as_float(u2.x << 16), q2, a0);
        a1 = fmaf(__uint_as_float(u2.x & 0xffff0000u), q2, a1);
        a2 = fmaf(__uint_as_float(u2.y << 16), q2, a2);
        c0 = fmaf(__uint_as_float(u3.x << 16), q3, c0);
        c1 = fmaf(__uint_as_float(u3.x & 0xffff0000u), q3, c1);
        c2 = fmaf(__uint_as_float(u3.y << 16), q3, c2);
    }
    for (; i < deg; i++) {
        int s = __shfl(myedge, i);
        float q = __shfl(myq, i);
        uint2 u = slab[(s << 6) + t];
        a0 = fmaf(__uint_as_float(u.x << 16), q, a0);
        a1 = fmaf(__uint_as_float(u.x & 0xffff0000u), q, a1);
        a2 = fmaf(__uint_as_float(u.y << 16), q, a2);
    }
    a0 += c0; a1 += c1; a2 += c2;
    float cd = rsqrtf(fmaxf((float)deg, 1.0f));
    a0 *= cd; a1 *= cd; a2 *= cd;

    float part = 0.f;
#pragma unroll 8
    for (int f = 0; f < 64; f++) {
        float4 wv = sW14[f];
        float h = fmaf(a0, wv.x, fmaf(a1, wv.y, fmaf(a2, wv.z, wv.w)));
        part = fmaf(fmaxf(h, 0.f), sWfc[w][f], part);
    }
    red[w][t] = part;
    __syncthreads();
    if (w == 0) {
        float tot = (red[0][t] + red[1][t]) + (red[2][t] + red[3][t]);
        atomicAdd(&bins[(g & 15) * 256 + bq * 64 + t], tot);   // 64 RMWs/address
        __threadfence();
        if (t == 0) lastflag = (atomicAdd(ticket, 1) == 4095);
    }
    __syncthreads();
    if (lastflag) {
        int b = threadIdx.x;
        float v = 0.f;
#pragma unroll
        for (int j = 0; j < 16; j++) v += atomicAdd(&bins[j * 256 + b], 0.0f);
        v += bfc[0];
        out[b] = 1.0f / (1.0f + expf(-v));
    }
}

extern "C" void kernel_launch(void* const* d_in, const int* in_sizes, int n_in,
                              void* d_out, int out_size, void* d_ws, size_t ws_size,
                              hipStream_t stream) {
    const float* x   = (const float*)d_in[0];
    const float* W1  = (const float*)d_in[1];
    const float* b1  = (const float*)d_in[2];
    const float* Wfc = (const float*)d_in[3];
    const float* bfc = (const float*)d_in[4];
    const int*   src = (const int*)d_in[5];
    const int*   dst = (const int*)d_in[6];
    float* out = (float*)d_out;

    char* ws = (char*)d_ws;
    uint2* xsb = (uint2*)ws;                       // 4 slabs x 2 MB = 8,388,608 B
    const size_t Z = (size_t)4 * Nn * 64 * 8;
    // zeroed ctrl block: deg_out | cursor | bins | done | ticket = 49160 B
    int*   deg_out = (int*)(ws + Z);
    int*   cursor  = (int*)(ws + Z + 16384);
    float* bins    = (float*)(ws + Z + 32768);     // 16*256 floats
    int*   done    = (int*)(ws + Z + 49152);
    int*   ticket  = (int*)(ws + Z + 49156);
    // not zeroed:
    float* c_srcf  = (float*)(ws + Z + 49408);     // 4096 floats
    int*   csr     = (int*)(ws + Z + 65792);       // 4096*64 ints = 1 MB

    hipMemsetAsync(ws + Z, 0, 49160, stream);
    k_pt<<<512, 256, 0, stream>>>(x, src, dst, deg_out, cursor, csr, done, c_srcf, xsb);
    k_mega<<<1024 * 4, 256, 0, stream>>>(xsb, W1, b1, Wfc, cursor, csr, c_srcf,
                                         bins, ticket, bfc, out);
}

// Round 10
// 112.645 us; speedup vs baseline: 1.8805x; 1.8805x over previous
//
#include <hip/hip_runtime.h>
#include <math.h>

#define Bg 256
#define Nn 4096
#define Ee 65536
#define Kk (Nn * 3)   // 12288

__device__ __forceinline__ unsigned bf16r(float v) {   // fp32 -> bf16 bits, RNE
    unsigned b = __float_as_uint(v);
    return (b + 0x7fffu + ((b >> 16) & 1u)) >> 16;
}

// ---------------- fused prep + transpose (independent halves, NO fences) -------------
// blocks [0,256): raw-bf16 transpose of x into 4 batch slabs (no scale baked in)
// blocks [256,512): edge prep (deg_out histogram + capacity-64 CSR by dst)
__global__ __launch_bounds__(256) void k_pt(const float* __restrict__ x,
                                            const int* __restrict__ src,
                                            const int* __restrict__ dst,
                                            int* __restrict__ deg_out,
                                            int* __restrict__ cursor,
                                            int* __restrict__ csr,
                                            uint2* __restrict__ xsb) {
    int id = blockIdx.x;
    int t = threadIdx.x;
    if (id < 256) {
        __shared__ float4 tile4[64][49];           // row stride 196 floats
        int bq = id >> 6;                          // batch slab [0,4)
        int n0 = (id & 63) * 64;                   // node group
        const float* xb = x + (size_t)bq * 64 * Kk + (size_t)n0 * 3;
#pragma unroll
        for (int i = 0; i < 12; i++) {
            int idx = i * 256 + t;
            int bi = idx / 48, j = idx - bi * 48;
            tile4[bi][j] = ((const float4*)(xb + (size_t)bi * Kk))[j];
        }
        __syncthreads();
        const float* tile = (const float*)tile4;   // [64][196]
        uint2* outp = xsb + ((size_t)bq * Nn + n0) * 64;
#pragma unroll
        for (int i = 0; i < 16; i++) {
            int idx = i * 256 + t;
            int nn = idx >> 6, bl = idx & 63;      // per wave: nn fixed, bl = lane
            float f0 = tile[bl * 196 + nn * 3 + 0];
            float f1 = tile[bl * 196 + nn * 3 + 1];
            float f2 = tile[bl * 196 + nn * 3 + 2];
            uint2 u;
            u.x = bf16r(f0) | (bf16r(f1) << 16);
            u.y = bf16r(f2);
            outp[(size_t)nn * 64 + bl] = u;
        }
    } else {
        int e = (id - 256) * 256 + t;
        int s = src[e], d = dst[e];
        atomicAdd(&deg_out[s], 1);
        int ofs = atomicAdd(&cursor[d], 1) & 63;   // capacity 64 (max in-deg ~35 << 64)
        csr[(d << 6) + ofs] = s;
    }
}

// ---------------- fused gather + c_src + (3->64) matmul + relu + Wfc dot -------------
// 4 waves/block, one node per wave; lane = batch element within slab.
// Per wave, ONE csr row load + ONE deg_out gather + one v_rsq; (s,q) pairs
// broadcast via __shfl. Inner loop: pure coalesced dwordx2 gathers + fmaf.
// Epilogue: plain coalesced 256 B store (no atomics, no fences).
__global__ __launch_bounds__(256) void k_main(const uint2* __restrict__ xsb,
                                              const float* __restrict__ W1,
                                              const float* __restrict__ b1,
                                              const float* __restrict__ Wfc,
                                              const int* __restrict__ deg_out,
                                              const int* __restrict__ cursor,
                                              const int* __restrict__ csr,
                                              float* __restrict__ partial) {
    __shared__ float4 sW14[64];
    __shared__ float sWfc[4][64];
    __shared__ float red[4][64];
    int t = threadIdx.x & 63;
    int w = threadIdx.x >> 6;
    int bq = blockIdx.x & 3;            // slab; round-robin dispatch -> L2 locality
    int g  = blockIdx.x >> 2;           // node group [0,1024)
    int n  = g * 4 + w;
    if (w == 0) sW14[t] = make_float4(W1[t], W1[64 + t], W1[128 + t], b1[t]);
    sWfc[w][t] = Wfc[n * 64 + t];
    __syncthreads();

    const uint2* slab = xsb + (size_t)bq * (Nn * 64);
    int deg = cursor[n]; if (deg > 64) deg = 64;
    int myedge = csr[(n << 6) + t];     // whole edge list in one wave load
    if (t >= deg) myedge = 0;           // unused slots may hold poison -> clamp
    float myq = rsqrtf(fmaxf((float)deg_out[myedge], 1.0f));  // one gather + one v_rsq per wave
    float a0 = 0.f, a1 = 0.f, a2 = 0.f;
    float c0 = 0.f, c1 = 0.f, c2 = 0.f;
    int i = 0;
    for (; i + 4 <= deg; i += 4) {
        int s0 = __shfl(myedge, i);     float q0 = __shfl(myq, i);
        int s1 = __shfl(myedge, i + 1); float q1 = __shfl(myq, i + 1);
        int s2 = __shfl(myedge, i + 2); float q2 = __shfl(myq, i + 2);
        int s3 = __shfl(myedge, i + 3); float q3 = __shfl(myq, i + 3);
        uint2 u0 = slab[(s0 << 6) + t];
        uint2 u1 = slab[(s1 << 6) + t];
        uint2 u2 = slab[(s2 << 6) + t];
        uint2 u3 = slab[(s3 << 6) + t];
        a0 = fmaf(__uint_as_float(u0.x << 16), q0, a0);
        a1 = fmaf(__uint_as_float(u0.x & 0xffff0000u), q0, a1);
        a2 = fmaf(__uint_as_float(u0.y << 16), q0, a2);
        c0 = fmaf(__uint_as_float(u1.x << 16), q1, c0);
        c1 = fmaf(__uint_as_float(u1.x & 0xffff0000u), q1, c1);
        c2 = fmaf(__uint_as_float(u1.y << 16), q1, c2);
        a0 = fmaf(__uint_as_float(u2.x << 16), q2, a0);
        a1 = fmaf(__uint_as_float(u2.x & 0xffff0000u), q2, a1);
        a2 = fmaf(__uint_as_float(u2.y << 16), q2, a2);
        c0 = fmaf(__uint_as_float(u3.x << 16), q3, c0);
        c1 = fmaf(__uint_as_float(u3.x & 0xffff0000u), q3, c1);
        c2 = fmaf(__uint_as_float(u3.y << 16), q3, c2);
    }
    for (; i < deg; i++) {
        int s = __shfl(myedge, i);
        float q = __shfl(myq, i);
        uint2 u = slab[(s << 6) + t];
        a0 = fmaf(__uint_as_float(u.x << 16), q, a0);
        a1 = fmaf(__uint_as_float(u.x & 0xffff0000u), q, a1);
        a2 = fmaf(__uint_as_float(u.y << 16), q, a2);
    }
    a0 += c0; a1 += c1; a2 += c2;
    float cd = rsqrtf(fmaxf((float)deg, 1.0f));
    a0 *= cd; a1 *= cd; a2 *= cd;

    float part = 0.f;
#pragma unroll 8
    for (int f = 0; f < 64; f++) {
        float4 wv = sW14[f];
        float h = fmaf(a0, wv.x, fmaf(a1, wv.y, fmaf(a2, wv.z, wv.w)));
        part = fmaf(fmaxf(h, 0.f), sWfc[w][f], part);
    }
    red[w][t] = part;
    __syncthreads();
    if (w == 0) {
        float tot = (red[0][t] + red[1][t]) + (red[2][t] + red[3][t]);
        partial[(size_t)g * 256 + bq * 64 + t] = tot;   // coalesced 256 B
    }
}

// ---------------- reduce partials + (last of 64 blocks) sigmoid ----------------
// Fence/ticket confined to 64 blocks — measured benign at this scale (r5/r6).
__global__ __launch_bounds__(256) void k_reduce_final(const float* __restrict__ partial,
                                                      float* __restrict__ out_acc,
                                                      int* __restrict__ ticket,
                                                      const float* __restrict__ bfc,
                                                      float* __restrict__ out) {
    __shared__ int lastflag;
    int t = threadIdx.x;
    int g0 = blockIdx.x * 16;
    float s = 0.f;
#pragma unroll
    for (int g = 0; g < 16; g++) s += partial[(size_t)(g0 + g) * 256 + t];
    atomicAdd(&out_acc[t], s);
    __threadfence();
    __syncthreads();
    if (t == 0) lastflag = (atomicAdd(ticket, 1) == 63);
    __syncthreads();
    if (lastflag) {
        float v = atomicAdd(&out_acc[t], 0.0f) + bfc[0];   // read-through coherence point
        out[t] = 1.0f / (1.0f + expf(-v));
    }
}

extern "C" void kernel_launch(void* const* d_in, const int* in_sizes, int n_in,
                              void* d_out, int out_size, void* d_ws, size_t ws_size,
                              hipStream_t stream) {
    const float* x   = (const float*)d_in[0];
    const float* W1  = (const float*)d_in[1];
    const float* b1  = (const float*)d_in[2];
    const float* Wfc = (const float*)d_in[3];
    const float* bfc = (const float*)d_in[4];
    const int*   src = (const int*)d_in[5];
    const int*   dst = (const int*)d_in[6];
    float* out = (float*)d_out;

    char* ws = (char*)d_ws;
    uint2* xsb = (uint2*)ws;                       // 4 slabs x 2 MB = 8,388,608 B
    const size_t Z = (size_t)4 * Nn * 64 * 8;
    // zeroed ctrl block: deg_out | cursor | out_acc | ticket = 33796 B
    int*   deg_out = (int*)(ws + Z);
    int*   cursor  = (int*)(ws + Z + 16384);
    float* out_acc = (float*)(ws + Z + 32768);
    int*   ticket  = (int*)(ws + Z + 33792);
    // not zeroed:
    int*   csr     = (int*)(ws + Z + 33920);       // 4096*64 ints = 1 MB
    float* partial = (float*)(ws + Z + 33920 + 1048576);   // 1024*256 floats = 1 MB

    hipMemsetAsync(ws + Z, 0, 33796, stream);
    k_pt<<<512, 256, 0, stream>>>(x, src, dst, deg_out, cursor, csr, xsb);
    k_main<<<1024 * 4, 256, 0, stream>>>(xsb, W1, b1, Wfc, deg_out, cursor, csr, partial);
    k_reduce_final<<<64, 256, 0, stream>>>(partial, out_acc, ticket, bfc, out);
}